// Round 11
// baseline (24.515 us; speedup 1.0000x reference)
//
#include <hip/hip_runtime.h>

#define B_ 1024
#define T_ 256
#define C_ 100
#define L_ 64
#define EPS_ 1e-7f
#define LN2 0.69314718055994530942f

#define CH 8               // timesteps per chunk
#define NCH 16             // chunks per direction (each wave covers 128 t)
#define DEPTH 6            // chunks in flight (9 loads each -> max 54 outstanding)

#define LOG2F(x) __builtin_amdgcn_logf(x)    // v_log_f32: log2(x)

typedef const __attribute__((address_space(1))) void GV;
typedef __attribute__((address_space(3))) void LV;

// async global->LDS, 4B per lane; LDS dest = uniform base + lane*4 (m104)
__device__ __forceinline__ void gload_lds4(const void* g, void* l) {
    __builtin_amdgcn_global_load_lds((GV*)g, (LV*)l, 4, 0, 0);
}

// whole-wave shifts via DPP; out-of-range lanes get 0 (old=0, bound_ctrl=false)
__device__ __forceinline__ float dpp_shr1(float x) {   // lane i <- lane i-1
    return __int_as_float(__builtin_amdgcn_update_dpp(
        0, __float_as_int(x), 0x138, 0xf, 0xf, false));
}
__device__ __forceinline__ float dpp_shl1(float x) {   // lane i <- lane i+1
    return __int_as_float(__builtin_amdgcn_update_dpp(
        0, __float_as_int(x), 0x130, 0xf, 0xf, false));
}

// Rescale plan: wave-max -> 2^K lifting max to ~1; normally applied one
// 8-step boundary later (stale -> butterfly latency hidden).
#define PLAN(x0_, x1_, x2_) do {                                          \
    float m_ = fmaxf(fmaxf(x0_, x1_), x2_);                               \
    _Pragma("unroll")                                                     \
    for (int d_ = 1; d_ < 64; d_ <<= 1) m_ = fmaxf(m_, __shfl_xor(m_, d_)); \
    const int e_ = (__float_as_int(m_) >> 23) & 255;                      \
    rs_K = 127 - e_;                                                      \
    rs_scale = __int_as_float((254 - e_) << 23);  /* 2^(127-e) */         \
} while (0)

#define APPLY(x0_, x1_, x2_) do { x0_ *= rs_scale; x1_ *= rs_scale;       \
    x2_ *= rs_scale; Sacc += rs_K; } while (0)

// forward step: lane i owns alpha{2i, 2i+1}; lane 63 also alpha{128}
#define FSTEP(pb_, pl_) do {                                              \
    const float up1 = dpp_shr1(a1);                                       \
    const float s   = allow ? up1 : 0.0f;                                 \
    const float n0  = (a0 + up1) * (pb_);                                 \
    const float n1  = ((a1 + a0) + s) * (pl_);                            \
    const float n2  = (a2 + a1) * (pb_);                                  \
    a0 = n0; a1 = n1; a2 = n2;                                            \
} while (0)

// backward step: lane i owns beta{2i, 2i+1}; lane 63 also beta{128}
#define BSTEP(pb_, pl_) do {                                              \
    const float db0 = dpp_shl1(a0);                                       \
    const float db1 = dpp_shl1(a1);                                       \
    const float sc0 = is63 ? a2 : db0;                                    \
    const float sk  = allowN ? db1 : 0.0f;   /* db1=0 at lane63 anyway */ \
    const float n0  = (a0 + a1) * (pb_);                                  \
    const float n1  = ((a1 + sc0) + sk) * (pl_);                          \
    const float n2  = a2 * (pb_);                                         \
    a0 = n0; a1 = n1; a2 = n2;                                            \
} while (0)

// folds to a single literal vmcnt under full unroll (c_ compile-time)
#define WAIT_CHUNK(c_) do {                                               \
    const int n_ = 9 * ((NCH - 1 - (c_)) < (DEPTH - 1) ? (NCH - 1 - (c_)) \
                                                       : (DEPTH - 1));    \
    switch (n_) {                                                         \
    case 45: asm volatile("s_waitcnt vmcnt(45)" ::: "memory"); break;     \
    case 36: asm volatile("s_waitcnt vmcnt(36)" ::: "memory"); break;     \
    case 27: asm volatile("s_waitcnt vmcnt(27)" ::: "memory"); break;     \
    case 18: asm volatile("s_waitcnt vmcnt(18)" ::: "memory"); break;     \
    case  9: asm volatile("s_waitcnt vmcnt(9)"  ::: "memory"); break;     \
    default: asm volatile("s_waitcnt vmcnt(0)"  ::: "memory"); break;     \
    }                                                                     \
} while (0)

// issue chunk c_ of this wave's direction: 8 label gathers + 1 packed blank
#define ISSUE(wv_, c_, toff_expr, boff_expr) do {                         \
    _Pragma("unroll")                                                     \
    for (int j_ = 0; j_ < CH; ++j_)                                       \
        gload_lds4(pL + (toff_expr) * C_, &plbuf[wv_][(c_) & 7][j_][0]);  \
    gload_lds4(pBlane + (boff_expr) * C_, &pbbuf[wv_][(c_) & 7][0]);      \
} while (0)

// Block = 2 waves per batch element: wave 0 = forward alpha (t=0..127),
// wave 1 = backward beta (t=255..128); combine P = sum_s alpha*gamma via LDS.
__global__ __launch_bounds__(128) void ctc_kernel(
    const int* __restrict__ y_true,
    const float* __restrict__ y_pred,
    float* __restrict__ out)
{
    __shared__ float plbuf[2][8][CH][64];   // 32 KB: label probs, lane-indexed
    __shared__ float pbbuf[2][8][64];       // 4 KB: blank probs (slots 0..7 used)
    __shared__ float sG0[64], sG1[64];
    __shared__ float sG2;
    __shared__ int   sSaccB;

    const int tid  = threadIdx.x;
    const int lane = tid & 63;
    const int wv   = tid >> 6;              // 0 = alpha, 1 = beta
    const int b    = blockIdx.x;

    const float* __restrict__ base = y_pred + (size_t)b * T_ * C_;
    const int  label   = y_true[b * L_ + lane];
    const int  labprev = __shfl_up(label, 1);
    const bool allow   = (lane == 0) || (label != labprev);
    const bool is63    = (lane == 63);
    const bool allowN  = (bool)__shfl_down((int)allow, 1);  // lane63: unused

    const float* __restrict__ pL = base + label;

    float a0 = 0.0f, a1 = 0.0f, a2 = 0.0f;
    float rs_scale = 1.0f;
    int   rs_K = 0, Sacc = 0;

    if (wv == 0) {
        // ---------------- forward wave: t = c*8 + j ----------------
        const float* __restrict__ pBlane = base + (C_ - 1) + (lane & 7) * C_;
        #pragma unroll
        for (int c = 0; c < DEPTH; ++c) ISSUE(0, c, c * CH + j_, c * CH);

        #pragma unroll
        for (int c = 0; c < NCH; ++c) {
            WAIT_CHUNK(c);
            const int bi = c & 7;
            if (c == 0) {
                a0 = (lane == 0) ? (pbbuf[0][0][0] + EPS_) : 0.0f;
                a1 = (lane == 0) ? (plbuf[0][0][0][lane] + EPS_) : 0.0f;
                a2 = 0.0f;
                PLAN(a0, a1, a2);
                #pragma unroll
                for (int j = 1; j < CH; ++j)
                    FSTEP(pbbuf[0][bi][j] + EPS_, plbuf[0][bi][j][lane] + EPS_);
            } else {
                APPLY(a0, a1, a2);
                PLAN(a0, a1, a2);
                #pragma unroll
                for (int j = 0; j < CH; ++j)
                    FSTEP(pbbuf[0][bi][j] + EPS_, plbuf[0][bi][j][lane] + EPS_);
            }
            if (c + DEPTH < NCH) ISSUE(0, c + DEPTH, (c + DEPTH) * CH + j_, (c + DEPTH) * CH);
        }

        // epilogue rescale: lift stored alpha max into [1,2) so the
        // cross-wave product cannot underflow (R10 bug: 2^-112..-212 -> 0)
        APPLY(a0, a1, a2);
        PLAN(a0, a1, a2);
        APPLY(a0, a1, a2);
    } else {
        // ---------------- backward wave: t = 255 - (c*8 + j) ----------------
        const float* __restrict__ pBlane = base + (C_ - 1) + (T_ - 1 - (lane & 7)) * C_;
        #pragma unroll
        for (int c = 0; c < DEPTH; ++c) ISSUE(1, c, T_ - 1 - (c * CH + j_), -(c * CH));

        #pragma unroll
        for (int c = 0; c < NCH; ++c) {
            WAIT_CHUNK(c);
            const int bi = c & 7;
            if (c == 0) {
                // t = 255: paths end in state 127 (label L-1) or 128 (blank)
                a2 = pbbuf[1][0][0] + EPS_;                       // beta[128]
                a1 = is63 ? (plbuf[1][0][0][lane] + EPS_) : 0.0f; // beta[127]
                a0 = 0.0f;
                PLAN(a0, a1, a2);
                #pragma unroll
                for (int j = 1; j < CH; ++j)
                    BSTEP(pbbuf[1][bi][j] + EPS_, plbuf[1][bi][j][lane] + EPS_);
            } else {
                APPLY(a0, a1, a2);
                PLAN(a0, a1, a2);
                #pragma unroll
                for (int j = 0; j < CH; ++j)
                    BSTEP(pbbuf[1][bi][j] + EPS_, plbuf[1][bi][j][lane] + EPS_);
            }
            if (c + DEPTH < NCH) ISSUE(1, c + DEPTH, T_ - 1 - ((c + DEPTH) * CH + j_), -((c + DEPTH) * CH));
        }

        // epilogue rescale: lift stored beta max into [1,2)
        APPLY(a0, a1, a2);
        PLAN(a0, a1, a2);
        APPLY(a0, a1, a2);

        // gamma at the cut: gamma[s] = sum over succ(s) of betaInc[128][s']
        const float db0 = dpp_shl1(a0);
        const float db1 = dpp_shl1(a1);
        sG0[lane] = a0 + a1;
        sG1[lane] = a1 + (is63 ? a2 : db0) + (allowN ? db1 : 0.0f);
        if (is63) { sG2 = a2; sSaccB = Sacc; }
    }

    __syncthreads();

    if (wv == 0) {
        // P = sum_s alpha[127][s] * gamma[s]
        float prod = a0 * sG0[lane] + a1 * sG1[lane];
        if (is63) prod += a2 * sG2;
        #pragma unroll
        for (int d = 1; d < 64; d <<= 1) prod += __shfl_xor(prod, d);
        if (lane == 0)
            out[b] = -LN2 * (LOG2F(prod) - (float)(Sacc + sSaccB));
    }
}

extern "C" void kernel_launch(void* const* d_in, const int* in_sizes, int n_in,
                              void* d_out, int out_size, void* d_ws, size_t ws_size,
                              hipStream_t stream) {
    const int*   y_true = (const int*)d_in[0];
    const float* y_pred = (const float*)d_in[1];
    float*       out    = (float*)d_out;

    ctc_kernel<<<dim3(B_), dim3(128), 0, stream>>>(y_true, y_pred, out);
}

// Round 12
// 23.570 us; speedup vs baseline: 1.0401x; 1.0401x over previous
//
#include <hip/hip_runtime.h>

#define B_ 1024
#define T_ 256
#define C_ 100
#define L_ 64
#define EPS_ 1e-7f
#define LN2 0.69314718055994530942f

#define CH 8               // timesteps per chunk (3200 B contiguous)
#define NCH 16             // chunks per direction (each wave covers 128 t)
#define DEPTH 3            // chunks in flight beyond current (4 loads each)
#define BROW (T_ * C_ * 4) // bytes per batch element = 102400

#define LOG2F(x) __builtin_amdgcn_logf(x)    // v_log_f32: log2(x)

typedef const __attribute__((address_space(1))) void GV;
typedef __attribute__((address_space(3))) void LV;

// async global->LDS, 16B per lane; LDS dest = uniform base + lane*16 (m097/m104)
__device__ __forceinline__ void gload_lds16(const void* g, void* l) {
    __builtin_amdgcn_global_load_lds((GV*)g, (LV*)l, 16, 0, 0);
}

// whole-wave shifts via DPP; out-of-range lanes get 0 (old=0, bound_ctrl=false)
__device__ __forceinline__ float dpp_shr1(float x) {   // lane i <- lane i-1
    return __int_as_float(__builtin_amdgcn_update_dpp(
        0, __float_as_int(x), 0x138, 0xf, 0xf, false));
}
__device__ __forceinline__ float dpp_shl1(float x) {   // lane i <- lane i+1
    return __int_as_float(__builtin_amdgcn_update_dpp(
        0, __float_as_int(x), 0x130, 0xf, 0xf, false));
}

// Rescale plan: wave-max -> 2^K lifting max to ~1; applied one 8-step
// boundary later (stale -> butterfly latency hidden).
#define PLAN(x0_, x1_, x2_) do {                                          \
    float m_ = fmaxf(fmaxf(x0_, x1_), x2_);                               \
    _Pragma("unroll")                                                     \
    for (int d_ = 1; d_ < 64; d_ <<= 1) m_ = fmaxf(m_, __shfl_xor(m_, d_)); \
    const int e_ = (__float_as_int(m_) >> 23) & 255;                      \
    rs_K = 127 - e_;                                                      \
    rs_scale = __int_as_float((254 - e_) << 23);  /* 2^(127-e) */         \
} while (0)

#define APPLY(x0_, x1_, x2_) do { x0_ *= rs_scale; x1_ *= rs_scale;       \
    x2_ *= rs_scale; Sacc += rs_K; } while (0)

// forward step: lane i owns alpha{2i, 2i+1}; lane 63 also alpha{128}
#define FSTEP(pb_, pl_) do {                                              \
    const float up1 = dpp_shr1(a1);                                       \
    const float s   = allow ? up1 : 0.0f;                                 \
    const float n0  = (a0 + up1) * (pb_);                                 \
    const float n1  = ((a1 + a0) + s) * (pl_);                            \
    const float n2  = (a2 + a1) * (pb_);                                  \
    a0 = n0; a1 = n1; a2 = n2;                                            \
} while (0)

// backward step: lane i owns beta{2i, 2i+1}; lane 63 also beta{128}
#define BSTEP(pb_, pl_) do {                                              \
    const float db0 = dpp_shl1(a0);                                       \
    const float db1 = dpp_shl1(a1);                                       \
    const float sc0 = is63 ? a2 : db0;                                    \
    const float sk  = allowN ? db1 : 0.0f;                                \
    const float n0  = (a0 + a1) * (pb_);                                  \
    const float n1  = ((a1 + sc0) + sk) * (pl_);                          \
    const float n2  = a2 * (pb_);                                         \
    a0 = n0; a1 = n1; a2 = n2;                                            \
} while (0)

// wait until chunk c_'s 4 loads have landed (counted vmcnt, never 0 mid-loop)
#define WAITC(c_) do {                                                    \
    if ((c_) <= NCH - 3)      asm volatile("s_waitcnt vmcnt(8)" ::: "memory"); \
    else if ((c_) == NCH - 2) asm volatile("s_waitcnt vmcnt(4)" ::: "memory"); \
    else                      asm volatile("s_waitcnt vmcnt(0)" ::: "memory"); \
} while (0)

// stream chunk: 4 coalesced 1024B wave-loads covering 3200B of rows (+tail
// garbage in slot bytes [3200,4096)); offsets clamped to buffer end (OOB-safe)
#define SISSUE(wv_, c_, off0_) do {                                       \
    _Pragma("unroll")                                                     \
    for (int k_ = 0; k_ < 4; ++k_) {                                      \
        unsigned o_ = (unsigned)(off0_) + k_ * 1024u + ((unsigned)lane << 4); \
        o_ = o_ < (BROW - 16u) ? o_ : (BROW - 16u);                       \
        gload_lds16(bb + o_, &ring[wv_][(c_) & 3][k_ * 256]);             \
    }                                                                     \
} while (0)

// Block = 2 waves per batch element: wave 0 = forward alpha (t=0..127),
// wave 1 = backward beta (t=255..128); combine P = sum_s alpha*gamma via LDS.
__global__ __launch_bounds__(128) void ctc_kernel(
    const int* __restrict__ y_true,
    const float* __restrict__ y_pred,
    float* __restrict__ out)
{
    __shared__ float ring[2][4][1024];   // 32 KB: 4-slot ring x 2 waves, full rows
    __shared__ float sG0[64], sG1[64];
    __shared__ float sG2;
    __shared__ int   sSaccB;

    const int tid  = threadIdx.x;
    const int lane = tid & 63;
    const int wv   = tid >> 6;              // 0 = alpha, 1 = beta
    const int b    = blockIdx.x;

    const float* __restrict__ base = y_pred + (size_t)b * T_ * C_;
    const char*  __restrict__ bb   = (const char*)base;
    const int  label   = y_true[b * L_ + lane];
    const int  labprev = __shfl_up(label, 1);
    const bool allow   = (lane == 0) || (label != labprev);
    const bool is63    = (lane == 63);
    const bool allowN  = (bool)__shfl_down((int)allow, 1);  // lane63: unused

    float a0 = 0.0f, a1 = 0.0f, a2 = 0.0f;
    float rs_scale = 1.0f;
    int   rs_K = 0, Sacc = 0;

    if (wv == 0) {
        // ---------------- forward wave: chunk c = t in [8c, 8c+8) ----------------
        #pragma unroll
        for (int c = 0; c < DEPTH; ++c) SISSUE(0, c, c * 3200);

        #pragma unroll
        for (int c = 0; c < NCH; ++c) {
            WAITC(c);
            const float* __restrict__ sl = ring[0][c & 3];
            if (c == 0) {
                // t = 0: only states 0 (blank) and 1 (first label), lane 0
                a0 = (lane == 0) ? (sl[99] + EPS_) : 0.0f;
                a1 = (lane == 0) ? (sl[label] + EPS_) : 0.0f;
                a2 = 0.0f;
                PLAN(a0, a1, a2);
                #pragma unroll
                for (int j = 1; j < CH; ++j)
                    FSTEP(sl[j * 100 + 99] + EPS_, sl[j * 100 + label] + EPS_);
            } else {
                APPLY(a0, a1, a2);
                PLAN(a0, a1, a2);
                #pragma unroll
                for (int j = 0; j < CH; ++j)
                    FSTEP(sl[j * 100 + 99] + EPS_, sl[j * 100 + label] + EPS_);
            }
            if (c + DEPTH < NCH) SISSUE(0, c + DEPTH, (c + DEPTH) * 3200);
        }

        // epilogue rescale: lift stored alpha max into [1,2) (avoid product underflow)
        APPLY(a0, a1, a2);
        PLAN(a0, a1, a2);
        APPLY(a0, a1, a2);
    } else {
        // ------------- backward wave: chunk c = t in [248-8c, 256-8c) -------------
        #pragma unroll
        for (int c = 0; c < DEPTH; ++c) SISSUE(1, c, 99200 - c * 3200);

        #pragma unroll
        for (int c = 0; c < NCH; ++c) {
            WAITC(c);
            const float* __restrict__ sl = ring[1][c & 3];
            if (c == 0) {
                // t = 255 (slot row 7): paths end in state 127 or 128
                a2 = sl[799] + EPS_;                          // beta[128]
                a1 = is63 ? (sl[700 + label] + EPS_) : 0.0f;  // beta[127]
                a0 = 0.0f;
                PLAN(a0, a1, a2);
                #pragma unroll
                for (int j = 1; j < CH; ++j)
                    BSTEP(sl[(7 - j) * 100 + 99] + EPS_, sl[(7 - j) * 100 + label] + EPS_);
            } else {
                APPLY(a0, a1, a2);
                PLAN(a0, a1, a2);
                #pragma unroll
                for (int j = 0; j < CH; ++j)
                    BSTEP(sl[(7 - j) * 100 + 99] + EPS_, sl[(7 - j) * 100 + label] + EPS_);
            }
            if (c + DEPTH < NCH) SISSUE(1, c + DEPTH, 99200 - (c + DEPTH) * 3200);
        }

        // epilogue rescale: lift stored beta max into [1,2)
        APPLY(a0, a1, a2);
        PLAN(a0, a1, a2);
        APPLY(a0, a1, a2);

        // gamma at the cut: gamma[s] = sum over succ(s) of beta[t=128][s']
        const float db0 = dpp_shl1(a0);
        const float db1 = dpp_shl1(a1);
        sG0[lane] = a0 + a1;
        sG1[lane] = a1 + (is63 ? a2 : db0) + (allowN ? db1 : 0.0f);
        if (is63) { sG2 = a2; sSaccB = Sacc; }
    }

    __syncthreads();

    if (wv == 0) {
        // P = sum_s alpha[127][s] * gamma[s]
        float prod = a0 * sG0[lane] + a1 * sG1[lane];
        if (is63) prod += a2 * sG2;
        #pragma unroll
        for (int d = 1; d < 64; d <<= 1) prod += __shfl_xor(prod, d);
        if (lane == 0)
            out[b] = -LN2 * (LOG2F(prod) - (float)(Sacc + sSaccB));
    }
}

extern "C" void kernel_launch(void* const* d_in, const int* in_sizes, int n_in,
                              void* d_out, int out_size, void* d_ws, size_t ws_size,
                              hipStream_t stream) {
    const int*   y_true = (const int*)d_in[0];
    const float* y_pred = (const float*)d_in[1];
    float*       out    = (float*)d_out;

    ctc_kernel<<<dim3(B_), dim3(128), 0, stream>>>(y_true, y_pred, out);
}